// Round 2
// baseline (176.925 us; speedup 1.0000x reference)
//
#include <hip/hip_runtime.h>

// y[b,c,0] = x[b,c,0];  y[b,c,n] = 0.3*x[n] + 0.7*y[n-1]  along axis 2 (N=32)
// Shapes: [4, 3, 32, 256, 256] fp32. Memory-bound; x is L3-resident on replay,
// floor ~= write drain 100.7 MB + L3 reads => ~20-25 us.
//
// R1 lesson: compiler serialized the per-frame loop (VGPR=32, 1 load in
// flight, 2.2 TB/s). Fix: explicit 8-frame load batches, double-buffered, so
// 8 independent global_load_dwordx4 are outstanding per wave.

constexpr int   BC  = 4 * 3;
constexpr int   NFR = 32;
constexpr int   HW4 = (256 * 256) / 4;   // float4 per frame-plane = 16384
constexpr int   G   = 8;                 // frames per batch
constexpr int   NG  = NFR / G;           // 4 groups
constexpr float WF  = 0.3f;
constexpr float OMW = 1.0f - WF;

__global__ __launch_bounds__(256) void recfilt_kernel(const float4* __restrict__ x,
                                                      float4* __restrict__ y) {
    const int p  = blockIdx.x * blockDim.x + threadIdx.x;
    const int bc = p >> 14;              // / HW4
    const int hw = p & (HW4 - 1);        // % HW4
    const long base = (long)bc * NFR * HW4 + hw;

    float4 buf[2][G];

    // Prefetch group 0 (frames 0..7)
#pragma unroll
    for (int j = 0; j < G; ++j)
        buf[0][j] = x[base + (long)j * HW4];

    float4 acc;
#pragma unroll
    for (int g = 0; g < NG; ++g) {
        // Prefetch next group before consuming current one.
        if (g + 1 < NG) {
#pragma unroll
            for (int j = 0; j < G; ++j)
                buf[(g + 1) & 1][j] = x[base + (long)((g + 1) * G + j) * HW4];
        }
        // Consume current group: dependent FMA chain + stores.
#pragma unroll
        for (int j = 0; j < G; ++j) {
            const int n = g * G + j;
            const float4 xv = buf[g & 1][j];
            if (n == 0) {
                acc = xv;
            } else {
                acc.x = WF * xv.x + OMW * acc.x;
                acc.y = WF * xv.y + OMW * acc.y;
                acc.z = WF * xv.z + OMW * acc.z;
                acc.w = WF * xv.w + OMW * acc.w;
            }
            y[base + (long)n * HW4] = acc;
        }
    }
}

extern "C" void kernel_launch(void* const* d_in, const int* in_sizes, int n_in,
                              void* d_out, int out_size, void* d_ws, size_t ws_size,
                              hipStream_t stream) {
    const float4* x = (const float4*)d_in[0];
    float4*       y = (float4*)d_out;
    const int chains = BC * HW4;              // 196,608 threads
    const int block  = 256;
    const int grid   = chains / block;        // 768 blocks = 12 waves/CU
    recfilt_kernel<<<grid, block, 0, stream>>>(x, y);
}